// Round 10
// baseline (231.655 us; speedup 1.0000x reference)
//
#include <hip/hip_runtime.h>
#include <stdint.h>

#define LDS_AS __attribute__((address_space(3)))
#define GLB_AS __attribute__((address_space(1)))

typedef unsigned short bfu;                                    // bf16 bit pattern
typedef __attribute__((ext_vector_type(8))) short short8;      // MFMA A/B frag (8 bf16)
typedef __attribute__((ext_vector_type(16))) float f32x16;     // 32x32 MFMA C/D frag

static constexpr int B_  = 8192;
static constexpr int D_  = 1024;
static constexpr int E_  = 16;
static constexpr int H_  = 256;
static constexpr int EH_ = E_ * H_;     // 4096

__device__ __forceinline__ bfu f2b(float f) {
  unsigned u = __float_as_uint(f);
  u = (u + 0x7FFFu + ((u >> 16) & 1u)) >> 16;   // RNE, finite data
  return (bfu)u;
}
__device__ __forceinline__ float b2f(bfu b) {
  return __uint_as_float(((unsigned)b) << 16);
}

__device__ __forceinline__ void gload_lds16(const bfu* g, bfu* l) {
  __builtin_amdgcn_global_load_lds((const GLB_AS void*)g, (LDS_AS void*)l, 16, 0, 0);
}

// ---------------- converts ----------------
__global__ void k_f32_to_bf16(const float* __restrict__ in, bfu* __restrict__ out, int n4) {
  int i = blockIdx.x * 256 + threadIdx.x;
  if (i >= n4) return;
  float4 v = reinterpret_cast<const float4*>(in)[i];
  ushort4 o;
  o.x = f2b(v.x); o.y = f2b(v.y); o.z = f2b(v.z); o.w = f2b(v.w);
  reinterpret_cast<ushort4*>(out)[i] = o;
}

// W2 [E][D][H] f32 -> W2t [D][EH_] bf16 with W2t[d][e*256+h] = W2[e][d][h]
__global__ void k_w2_transpose(const float* __restrict__ W2, bfu* __restrict__ W2t) {
  int i = blockIdx.x * 256 + threadIdx.x;   // [0, 16*1024*64)
  if (i >= E_ * D_ * (H_ / 4)) return;
  int h4 = i & 63;
  int d  = (i >> 6) & (D_ - 1);
  int e  = i >> 16;
  float4 v = reinterpret_cast<const float4*>(W2)[((e << 10) | d) * 64 + h4];
  ushort4 o;
  o.x = f2b(v.x); o.y = f2b(v.y); o.z = f2b(v.z); o.w = f2b(v.w);
  reinterpret_cast<ushort4*>(W2t + ((size_t)d << 12) + (e << 8))[h4] = o;
}

// ---------------- router (fp32, exact) ----------------
__global__ __launch_bounds__(256)
void k_router(const float* __restrict__ cond, const float* __restrict__ Wr1,
              const float* __restrict__ br1, const float* __restrict__ Wr2,
              const float* __restrict__ br2, float* __restrict__ route) {
  __shared__ float sW1[128][65];
  __shared__ float sW2[16][129];
  __shared__ float sb1[128], sb2[16];
  __shared__ float sc[2][64];
  __shared__ float srh[2][128];
  const int t = threadIdx.x;
  for (int i = t; i < 128 * 64; i += 256) sW1[i >> 6][i & 63] = Wr1[i];
  for (int i = t; i < 16 * 128; i += 256) sW2[i >> 7][i & 127] = Wr2[i];
  if (t < 128) sb1[t] = br1[t];
  else if (t < 144) sb2[t - 128] = br2[t - 128];
  const int rowBase = blockIdx.x * 32;
  for (int r0 = 0; r0 < 32; r0 += 2) {
    __syncthreads();
    if (t < 128) sc[t >> 6][t & 63] = cond[(size_t)(rowBase + r0 + (t >> 6)) * 64 + (t & 63)];
    __syncthreads();
    {
      const int half = t >> 7, j = t & 127;
      float a = sb1[j];
      #pragma unroll 16
      for (int c = 0; c < 64; ++c) a = fmaf(sc[half][c], sW1[j][c], a);
      srh[half][j] = fmaxf(a, 0.f);
    }
    __syncthreads();
    if (t < 32) {
      const int half = t >> 4, e = t & 15;
      float a = sb2[e];
      #pragma unroll 16
      for (int k = 0; k < 128; ++k) a = fmaf(srh[half][k], sW2[e][k], a);
      float mx = a;
      #pragma unroll
      for (int m = 8; m; m >>= 1) mx = fmaxf(mx, __shfl_xor(mx, m, 16));
      float p = __expf(a - mx);
      float s = p;
      #pragma unroll
      for (int m = 8; m; m >>= 1) s += __shfl_xor(s, m, 16);
      route[(size_t)(rowBase + r0 + half) * 16 + e] = p / s;
    }
  }
}

// ---- 128x256 GEMM-BT, BK=32, dbuf, LDS 48KB -> 2 blocks/CU ----
// 8 waves (2 wr x 4 wc), wave out 64x64 = 2mt x 2nt of 32x32x16 MFMA.
// Per K32-tile: 8 ds_read_b128 + 8 MFMA per wave, one __syncthreads.
// LDS (bytes): per buf 24576: A (128 rows x 64 B) @0, B (256 x 64 B) @8192.
// Swizzle: 64-B rows have 4 16-B slots; stored slot = gslot ^ ((row>>1)&3);
// read kterm = (ks*32 + lhi*16) ^ (((l31>>1)&3)<<4)  [2-way max, free].
// C/D: col = l&31, row = (r&3) + 8*(r>>2) + 4*(l>>5)  [HW-verified m74/m101].
// EPI=1: bf16 relu(acc+b1)*route -> Hp (N-tile 256 = expert width).
// EPI=2: split-K x2; chunk0 -> f32 out, chunk1 -> bf16 partial.

#define STAGE_A(tile_, buf_)                                                      \
  do {                                                                            \
    const int k0_ = kOff + ((tile_) << 5);                                        \
    const int row_ = tid >> 2;                                                    \
    const int gsl_ = (tid & 3) ^ ((row_ >> 1) & 3);                               \
    gload_lds16(A + (size_t)(brow + row_) * lda + k0_ + gsl_ * 8,                 \
                lds + (buf_) * 12288 + tid * 8);                                  \
  } while (0)

#define STAGE_B(tile_, buf_)                                                      \
  do {                                                                            \
    const int k0_ = kOff + ((tile_) << 5);                                        \
    _Pragma("unroll")                                                             \
    for (int j_ = 0; j_ < 2; ++j_) {                                              \
      const int c_ = (j_ << 9) | tid;                                             \
      const int row_ = c_ >> 2;                                                   \
      const int gsl_ = (c_ & 3) ^ ((row_ >> 1) & 3);                              \
      gload_lds16(Bm + (size_t)(bcol + row_) * ldb + k0_ + gsl_ * 8,              \
                  lds + (buf_) * 12288 + 4096 + c_ * 8);                          \
    }                                                                             \
  } while (0)

#define STAGE_TILE(tile_, buf_) do { STAGE_B(tile_, buf_); STAGE_A(tile_, buf_); } while (0)

// frag reads (BYTE addressing): buf/mt/nt are compile-time constants
#define LDA32(dst_, buf_, kt_, mt_)                                               \
  dst_ = *reinterpret_cast<const short8*>(                                        \
      ldsC + (buf_) * 24576 + aOff + (kt_) + ((mt_) << 11))

#define LDB32(dst_, buf_, kt_, nt_)                                               \
  dst_ = *reinterpret_cast<const short8*>(                                        \
      ldsC + (buf_) * 24576 + 8192 + bOff + (kt_) + ((nt_) << 11))

#define MFMA1(mt_, nt_, af_, bf_)                                                 \
  acc[mt_][nt_] = __builtin_amdgcn_mfma_f32_32x32x16_bf16(af_, bf_, acc[mt_][nt_], 0, 0, 0)

#define TILE_COMPUTE(c_)                                                          \
  do {                                                                            \
    short8 a0_, a1_, b0_, b1_, a2_, a3_, b2_, b3_;                                \
    LDA32(a0_, (c_), kt0, 0); LDA32(a1_, (c_), kt0, 1);                           \
    LDB32(b0_, (c_), kt0, 0); LDB32(b1_, (c_), kt0, 1);                           \
    LDA32(a2_, (c_), kt1, 0); LDA32(a3_, (c_), kt1, 1);                           \
    LDB32(b2_, (c_), kt1, 0); LDB32(b3_, (c_), kt1, 1);                           \
    MFMA1(0, 0, a0_, b0_); MFMA1(0, 1, a0_, b1_);                                 \
    MFMA1(1, 0, a1_, b0_); MFMA1(1, 1, a1_, b1_);                                 \
    MFMA1(0, 0, a2_, b2_); MFMA1(0, 1, a2_, b3_);                                 \
    MFMA1(1, 0, a3_, b2_); MFMA1(1, 1, a3_, b3_);                                 \
  } while (0)

template <int EPI>
__global__ __launch_bounds__(512, 4)
void k_gemm8(const bfu* __restrict__ A, int lda,
             const bfu* __restrict__ Bm, int ldb,
             int nkt,                       // K32-tiles (per chunk), even
             float* __restrict__ outF, bfu* __restrict__ outB, int ldc,
             const float* __restrict__ route, const float* __restrict__ bias1) {
  __shared__ __align__(16) bfu lds[24576];  // 48 KiB
  const char* ldsC = reinterpret_cast<const char*>(lds);
  const int tid = (int)threadIdx.x;
  const int w = tid >> 6, l = tid & 63;
  const int wr = w >> 2, wc = w & 3;
  const int l31 = l & 31, lhi = l >> 5;
  const unsigned swz = (unsigned)(((l31 >> 1) & 3) << 4);
  const unsigned kt0 = ((unsigned)(lhi << 4)) ^ swz;          // ks=0 slot {0,1}
  const unsigned kt1 = ((unsigned)(32 + (lhi << 4))) ^ swz;   // ks=1 slot {2,3}
  const unsigned aOff = (unsigned)((wr * 64 + l31) * 64);     // byte row off in A
  const unsigned bOff = (unsigned)((wc * 64 + l31) * 64);     // byte row off in B

  const int bid = (int)blockIdx.x;
  const int xcd = bid & 7;
  int brow, bcol, chunk = 0, kOff = 0;
  if (EPI == 1) {
    // grid 1024 = 64 rowtiles x 16 coltiles; XCD owns 8 consecutive row-tiles
    const int i = bid >> 3;                      // 0..127
    brow = ((xcd << 3) + (i >> 4)) << 7;
    bcol = (i & 15) << 8;
  } else {
    // grid 512 = (64 rowtiles x 4 coltiles) x 2 chunks
    const int i = bid >> 3;                      // 0..63
    chunk = i >> 5;
    const int ii = i & 31;
    brow = ((xcd << 3) + (ii >> 2)) << 7;
    bcol = (ii & 3) << 8;
    kOff = chunk << 11;                          // chunk * 2048 elements
  }

  f32x16 acc[2][2] = {};

  STAGE_TILE(0, 0);
  __syncthreads();

  for (int it = 0; it < (nkt >> 1); ++it) {
    const int T = it << 1;
    STAGE_TILE(T + 1, 1);
    TILE_COMPUTE(0);
    __syncthreads();
    if (T + 2 < nkt) STAGE_TILE(T + 2, 0);
    TILE_COMPUTE(1);
    __syncthreads();
  }

  // ---------- all-wave coalesced epilogue via padded LDS bounce ----------
  if (EPI == 1 || chunk == 1) {
    // bf16: 2 slices (s = mt); LDS [wr*32 + rloc][256], stride 264 bfu (33.8 KB)
    const int STR = 264;
    #pragma unroll
    for (int s = 0; s < 2; ++s) {
      float bz0 = 0.f, bz1 = 0.f;
      if (EPI == 1) {
        bz0 = bias1[bcol + wc * 64 + l31];
        bz1 = bias1[bcol + wc * 64 + 32 + l31];
      }
      #pragma unroll
      for (int r = 0; r < 16; ++r) {
        const int rloc = (r & 3) + 8 * (r >> 2) + 4 * lhi;   // 0..31
        float v0 = acc[s][0][r], v1 = acc[s][1][r];
        if (EPI == 1) {
          const int rowg = brow + wr * 64 + s * 32 + rloc;
          const float rt = route[(size_t)rowg * E_ + (bcol >> 8)];
          v0 = fmaxf(v0 + bz0, 0.f) * rt;
          v1 = fmaxf(v1 + bz1, 0.f) * rt;
        }
        lds[(wr * 32 + rloc) * STR + wc * 64 + l31] = f2b(v0);
        lds[(wr * 32 + rloc) * STR + wc * 64 + 32 + l31] = f2b(v1);
      }
      __syncthreads();
      #pragma unroll
      for (int i = 0; i < 4; ++i) {
        const int id = i * 512 + tid;            // 2048 x 16B chunks
        const int row = id >> 5, c16 = id & 31;  // row 0..63
        *reinterpret_cast<short8*>(
            outB + (size_t)(brow + (row >> 5) * 64 + s * 32 + (row & 31)) * ldc +
            bcol + c16 * 8) =
            *reinterpret_cast<const short8*>(lds + row * STR + c16 * 8);
      }
      __syncthreads();
    }
  } else {
    // f32: 4 slices (mt x rloc-half); LDS [wr*16 + rl16][256], stride 268 (34.3 KB)
    const int STRF = 268;
    float* sF = reinterpret_cast<float*>(const_cast<bfu*>(lds));
    #pragma unroll
    for (int s = 0; s < 4; ++s) {
      const int mt = s >> 1, half = s & 1;
      #pragma unroll
      for (int r8 = 0; r8 < 8; ++r8) {
        const int r = half * 8 + r8;
        const int rl16 = (r & 3) + 8 * ((r >> 2) & 1) + 4 * lhi;   // 0..15
        sF[(wr * 16 + rl16) * STRF + wc * 64 + l31] = acc[mt][0][r];
        sF[(wr * 16 + rl16) * STRF + wc * 64 + 32 + l31] = acc[mt][1][r];
      }
      __syncthreads();
      #pragma unroll
      for (int i = 0; i < 4; ++i) {
        const int id = i * 512 + tid;            // 2048 x 16B chunks
        const int row = id >> 6, c4 = id & 63;   // row 0..31
        *reinterpret_cast<float4*>(
            outF + (size_t)(brow + (row >> 4) * 64 + mt * 32 + half * 16 + (row & 15)) * ldc +
            bcol + c4 * 4) =
            *reinterpret_cast<const float4*>(sF + row * STRF + c4 * 4);
      }
      __syncthreads();
    }
  }
}

// ---------------- reduce: out += P1 + route @ b2 ----------------
__global__ __launch_bounds__(256)
void k_reduce(float* __restrict__ out, const bfu* __restrict__ P1,
              const float* __restrict__ route, const float* __restrict__ b2) {
  __shared__ float sb2[E_ * D_];   // 64 KiB
  for (int i = threadIdx.x; i < E_ * D_; i += 256) sb2[i] = b2[i];
  __syncthreads();
  const int total = (B_ * D_) / 4;
  for (int idx = blockIdx.x * 256 + threadIdx.x; idx < total; idx += gridDim.x * 256) {
    const int b = idx >> 8;
    const int d4 = (idx & 255) * 4;
    float4 o = reinterpret_cast<float4*>(out)[idx];
    ushort4 p = reinterpret_cast<const ushort4*>(P1)[idx];
    o.x += b2f(p.x); o.y += b2f(p.y); o.z += b2f(p.z); o.w += b2f(p.w);
    const float* rr = route + (size_t)b * E_;
    #pragma unroll
    for (int e = 0; e < E_; ++e) {
      const float r = rr[e];
      const float* bb = sb2 + e * D_ + d4;
      o.x = fmaf(r, bb[0], o.x);
      o.y = fmaf(r, bb[1], o.y);
      o.z = fmaf(r, bb[2], o.z);
      o.w = fmaf(r, bb[3], o.w);
    }
    reinterpret_cast<float4*>(out)[idx] = o;
  }
}

// ---------------- launch ----------------
extern "C" void kernel_launch(void* const* d_in, const int* in_sizes, int n_in,
                              void* d_out, int out_size, void* d_ws, size_t ws_size,
                              hipStream_t stream) {
  const float* x    = (const float*)d_in[0];
  const float* cond = (const float*)d_in[1];
  const float* W1   = (const float*)d_in[2];
  const float* b1   = (const float*)d_in[3];
  const float* W2   = (const float*)d_in[4];
  const float* b2   = (const float*)d_in[5];
  const float* Wr1  = (const float*)d_in[6];
  const float* br1  = (const float*)d_in[7];
  const float* Wr2  = (const float*)d_in[8];
  const float* br2  = (const float*)d_in[9];
  float* out = (float*)d_out;

  // ws layout (96.5 MB):
  // [Hp 64MB][W2t 8MB][route 0.5MB][W1b 8MB][xb 16MB (= P1 after GEMM1)]
  char* p = (char*)d_ws;
  bfu*   Hp    = (bfu*)p;                 p += (size_t)B_ * EH_ * 2;
  bfu*   W2t   = (bfu*)p;                 p += (size_t)D_ * EH_ * 2;
  float* route = (float*)p;               p += (size_t)B_ * E_ * 4;
  bfu*   W1b   = (bfu*)p;                 p += (size_t)EH_ * D_ * 2;
  bfu*   xb    = (bfu*)p;                 /* B_*D_*2 = 16MB */
  bfu*   P1b   = xb;                      // alias: xb dead after GEMM1

  k_f32_to_bf16<<<(B_ * D_ / 4 + 255) / 256, 256, 0, stream>>>(x, xb, B_ * D_ / 4);
  k_f32_to_bf16<<<(EH_ * D_ / 4 + 255) / 256, 256, 0, stream>>>(W1, W1b, EH_ * D_ / 4);
  k_w2_transpose<<<(E_ * D_ * (H_ / 4) + 255) / 256, 256, 0, stream>>>(W2, W2t);
  k_router<<<B_ / 32, 256, 0, stream>>>(cond, Wr1, br1, Wr2, br2, route);

  // GEMM1: Hp[8192,4096] = relu(xb @ W1b^T + b1) * route  (1024 blocks, 2/CU x2)
  k_gemm8<1><<<dim3(1024), 512, 0, stream>>>(
      xb, D_, W1b, D_, D_ / 32, nullptr, Hp, EH_, route, b1);

  // GEMM2: out/P1 = Hp @ W2t^T, split-K x2  (512 blocks, 2/CU)
  k_gemm8<2><<<dim3(512), 512, 0, stream>>>(
      Hp, EH_, W2t, EH_, (EH_ / 32) / 2, out, P1b, D_, nullptr, nullptr);

  // out += P1 + route @ b2
  k_reduce<<<2048, 256, 0, stream>>>(out, P1b, route, b2);
}

// Round 11
// 202.719 us; speedup vs baseline: 1.1427x; 1.1427x over previous
//
#include <hip/hip_runtime.h>
#include <stdint.h>

#define LDS_AS __attribute__((address_space(3)))
#define GLB_AS __attribute__((address_space(1)))

typedef unsigned short bfu;                                    // bf16 bit pattern
typedef __attribute__((ext_vector_type(8))) short short8;      // MFMA A/B frag (8 bf16)
typedef __attribute__((ext_vector_type(16))) float f32x16;     // 32x32 MFMA C/D frag

static constexpr int B_  = 8192;
static constexpr int D_  = 1024;
static constexpr int E_  = 16;
static constexpr int H_  = 256;
static constexpr int EH_ = E_ * H_;     // 4096

__device__ __forceinline__ bfu f2b(float f) {
  unsigned u = __float_as_uint(f);
  u = (u + 0x7FFFu + ((u >> 16) & 1u)) >> 16;   // RNE, finite data
  return (bfu)u;
}
__device__ __forceinline__ float b2f(bfu b) {
  return __uint_as_float(((unsigned)b) << 16);
}

__device__ __forceinline__ void gload_lds16(const bfu* g, bfu* l) {
  __builtin_amdgcn_global_load_lds((const GLB_AS void*)g, (LDS_AS void*)l, 16, 0, 0);
}

// ---------------- fused prep: x->bf16, W1->bf16, W2 transpose ----------------
__global__ __launch_bounds__(256)
void k_prep(const float* __restrict__ x, bfu* __restrict__ xb,
            const float* __restrict__ W1, bfu* __restrict__ W1b,
            const float* __restrict__ W2, bfu* __restrict__ W2t) {
  const int total = (int)gridDim.x * 256;
  const int gid = (int)blockIdx.x * 256 + (int)threadIdx.x;
  const int n1 = B_ * D_ / 4;     // 2,097,152
  const int n2 = EH_ * D_ / 4;    // 1,048,576
  const int n3 = E_ * D_ * 64;    // 1,048,576
  for (int i = gid; i < n1; i += total) {
    float4 v = reinterpret_cast<const float4*>(x)[i];
    ushort4 o;
    o.x = f2b(v.x); o.y = f2b(v.y); o.z = f2b(v.z); o.w = f2b(v.w);
    reinterpret_cast<ushort4*>(xb)[i] = o;
  }
  for (int i = gid; i < n2; i += total) {
    float4 v = reinterpret_cast<const float4*>(W1)[i];
    ushort4 o;
    o.x = f2b(v.x); o.y = f2b(v.y); o.z = f2b(v.z); o.w = f2b(v.w);
    reinterpret_cast<ushort4*>(W1b)[i] = o;
  }
  for (int i = gid; i < n3; i += total) {
    const int h4 = i & 63;
    const int d  = (i >> 6) & (D_ - 1);
    const int e  = i >> 16;
    float4 v = reinterpret_cast<const float4*>(W2)[((e << 10) | d) * 64 + h4];
    ushort4 o;
    o.x = f2b(v.x); o.y = f2b(v.y); o.z = f2b(v.z); o.w = f2b(v.w);
    reinterpret_cast<ushort4*>(W2t + ((size_t)d << 12) + (e << 8))[h4] = o;
  }
}

// ---------------- router (fp32, exact) ----------------
__global__ __launch_bounds__(256)
void k_router(const float* __restrict__ cond, const float* __restrict__ Wr1,
              const float* __restrict__ br1, const float* __restrict__ Wr2,
              const float* __restrict__ br2, float* __restrict__ route) {
  __shared__ float sW1[128][65];
  __shared__ float sW2[16][129];
  __shared__ float sb1[128], sb2[16];
  __shared__ float sc[2][64];
  __shared__ float srh[2][128];
  const int t = threadIdx.x;
  for (int i = t; i < 128 * 64; i += 256) sW1[i >> 6][i & 63] = Wr1[i];
  for (int i = t; i < 16 * 128; i += 256) sW2[i >> 7][i & 127] = Wr2[i];
  if (t < 128) sb1[t] = br1[t];
  else if (t < 144) sb2[t - 128] = br2[t - 128];
  const int rowBase = blockIdx.x * 16;
  for (int r0 = 0; r0 < 16; r0 += 2) {
    __syncthreads();
    if (t < 128) sc[t >> 6][t & 63] = cond[(size_t)(rowBase + r0 + (t >> 6)) * 64 + (t & 63)];
    __syncthreads();
    {
      const int half = t >> 7, j = t & 127;
      float a = sb1[j];
      #pragma unroll 16
      for (int c = 0; c < 64; ++c) a = fmaf(sc[half][c], sW1[j][c], a);
      srh[half][j] = fmaxf(a, 0.f);
    }
    __syncthreads();
    if (t < 32) {
      const int half = t >> 4, e = t & 15;
      float a = sb2[e];
      #pragma unroll 16
      for (int k = 0; k < 128; ++k) a = fmaf(srh[half][k], sW2[e][k], a);
      float mx = a;
      #pragma unroll
      for (int m = 8; m; m >>= 1) mx = fmaxf(mx, __shfl_xor(mx, m, 16));
      float p = __expf(a - mx);
      float s = p;
      #pragma unroll
      for (int m = 8; m; m >>= 1) s += __shfl_xor(s, m, 16);
      route[(size_t)(rowBase + r0 + half) * 16 + e] = p / s;
    }
  }
}

// ------ 256x256 GEMM-BT, R9 core + hoisted staging addresses ------
// 8 waves (2 wr x 4 wc), wave out 128x64 = 4mt x 2nt of 32x32x16 MFMA.
// Per K64-tile: 24 ds_read_b128 + 32 MFMA, one __syncthreads.
// Staging: 8 per-lane u64 pointers precomputed; each staged tile bumps +64 elem.
// LDS regions 16384 B: byte base = buf<<16 | region<<14 (A0,A1,B0,B1).
// C/D: col = l&31, row = (r&3) + 8*(r>>2) + 4*(l>>5)  [HW-verified m74/m101].

#define STAGE_TILE_P(buf_)                                                        \
  do {                                                                            \
    gload_lds16(pB00, lds + (((buf_) << 2 | 2) << 13) + tid * 8);                 \
    gload_lds16(pB01, lds + (((buf_) << 2 | 2) << 13) + 4096 + tid * 8);          \
    gload_lds16(pB10, lds + (((buf_) << 2 | 3) << 13) + tid * 8);                 \
    gload_lds16(pB11, lds + (((buf_) << 2 | 3) << 13) + 4096 + tid * 8);          \
    gload_lds16(pA00, lds + (((buf_) << 2 | 0) << 13) + tid * 8);                 \
    gload_lds16(pA01, lds + (((buf_) << 2 | 0) << 13) + 4096 + tid * 8);          \
    gload_lds16(pA10, lds + (((buf_) << 2 | 1) << 13) + tid * 8);                 \
    gload_lds16(pA11, lds + (((buf_) << 2 | 1) << 13) + 4096 + tid * 8);          \
    pA00 += 64; pA01 += 64; pA10 += 64; pA11 += 64;                               \
    pB00 += 64; pB01 += 64; pB10 += 64; pB11 += 64;                               \
  } while (0)

// frag reads (BYTE units): runtime base (per ks) + compile-time imm (mt/nt<<12)
#define LDA32(dst_, buf_, ksv_, mt_)                                              \
  dst_ = *reinterpret_cast<const short8*>(                                        \
      ldsC + (((buf_) << 16) | (wr << 14)) + aKs[ksv_] + ((mt_) << 12))

#define LDB32(dst_, buf_, ksv_, nt_)                                              \
  dst_ = *reinterpret_cast<const short8*>(                                        \
      ldsC + ((buf_) << 16) + bKs[ksv_] + ((nt_) << 12))

#define LDA32x4(dst_, buf_, ksv_)                                                 \
  _Pragma("unroll") for (int mt_ = 0; mt_ < 4; ++mt_) LDA32(dst_[mt_], buf_, ksv_, mt_)
#define LDB32x2(dst_, buf_, ksv_)                                                 \
  _Pragma("unroll") for (int nt_ = 0; nt_ < 2; ++nt_) LDB32(dst_[nt_], buf_, ksv_, nt_)

#define MFMA8(AF_, BF_)                                                           \
  _Pragma("unroll") for (int mt_ = 0; mt_ < 4; ++mt_)                             \
  _Pragma("unroll") for (int nt_ = 0; nt_ < 2; ++nt_)                             \
    acc[mt_][nt_] = __builtin_amdgcn_mfma_f32_32x32x16_bf16(                      \
        AF_[mt_], BF_[nt_], acc[mt_][nt_], 0, 0, 0);

#define TILE_COMPUTE(c_)                                                          \
  do {                                                                            \
    LDA32x4(aP_, (c_), 0); LDB32x2(bP_, (c_), 0);                                 \
    LDA32x4(aN_, (c_), 1); LDB32x2(bN_, (c_), 1);                                 \
    MFMA8(aP_, bP_);                                                              \
    LDA32x4(aP_, (c_), 2); LDB32x2(bP_, (c_), 2);                                 \
    MFMA8(aN_, bN_);                                                              \
    LDA32x4(aN_, (c_), 3); LDB32x2(bN_, (c_), 3);                                 \
    MFMA8(aP_, bP_);                                                              \
    MFMA8(aN_, bN_);                                                              \
  } while (0)

template <int EPI>
__global__ __launch_bounds__(512, 2)
void k_gemm8(const bfu* __restrict__ A, int lda,
             const bfu* __restrict__ Bm, int ldb,
             int nkt,                       // K64-tiles (per chunk), even, >= 2
             float* __restrict__ outF, bfu* __restrict__ outB, int ldc,
             const float* __restrict__ route, const float* __restrict__ bias1) {
  __shared__ __align__(16) bfu lds[65536];  // 128 KiB
  const char* ldsC = reinterpret_cast<const char*>(lds);
  const int tid = (int)threadIdx.x;
  const int w = tid >> 6, l = tid & 63;
  const int wr = w >> 2, wc = w & 3;
  const int l31 = l & 31, lhi = l >> 5;
  const unsigned axor = (unsigned)((l & 7) << 4);
  const int bhalfSel = wc >> 1;
  const int bInner = (wc & 1) << 13;

  unsigned aKs[4], bKs[4];
  #pragma unroll
  for (int ks = 0; ks < 4; ++ks) {
    const unsigned kterm = ((unsigned)((ks << 5) | (lhi << 4))) ^ axor;
    aKs[ks] = (unsigned)(l31 * 128) + kterm;
    bKs[ks] = (unsigned)(((2 | bhalfSel) << 14) + bInner + l31 * 128) + kterm;
  }

  const int bid = (int)blockIdx.x;
  const int xcd = bid & 7;
  int brow, bcol, chunk = 0, kOff = 0;
  if (EPI == 1) {
    const int i = bid >> 3;                       // grid 512: XCD owns 8x8 squares
    brow = (((xcd >> 1) << 3) + (i >> 3)) << 8;
    bcol = (((xcd & 1) << 3) + (i & 7)) << 8;
  } else {
    const int i = bid >> 3;                       // grid 256: 4-row slab per chunk
    chunk = i >> 4;
    const int ii = i & 15;
    brow = ((xcd << 2) + (ii >> 2)) << 8;
    bcol = (ii & 3) << 8;
    kOff = chunk * (nkt << 6);
  }

  // hoisted per-lane staging addresses (tile 0), swizzled source slot
  const int srow = tid >> 3;                                     // 0..63
  const int sswz = ((tid & 7) ^ (srow & 7)) << 3;                // element offset
  const bfu* pA00 = A + (size_t)(brow + srow) * lda + kOff + sswz;
  const bfu* pA01 = pA00 + (size_t)64 * lda;
  const bfu* pA10 = pA00 + (size_t)128 * lda;
  const bfu* pA11 = pA00 + (size_t)192 * lda;
  const bfu* pB00 = Bm + (size_t)(bcol + srow) * ldb + kOff + sswz;
  const bfu* pB01 = pB00 + (size_t)64 * ldb;
  const bfu* pB10 = pB00 + (size_t)128 * ldb;
  const bfu* pB11 = pB00 + (size_t)192 * ldb;

  f32x16 acc[4][2] = {};
  short8 aP_[4], aN_[4], bP_[2], bN_[2];

  STAGE_TILE_P(0);
  __syncthreads();

  for (int it = 0; it < (nkt >> 1); ++it) {
    const int T = it << 1;
    STAGE_TILE_P(1);
    TILE_COMPUTE(0);
    __syncthreads();
    if (T + 2 < nkt) STAGE_TILE_P(0);
    TILE_COMPUTE(1);
    __syncthreads();
  }

  // ---------- all-wave coalesced epilogue via padded LDS bounce ----------
  if (EPI == 1 || chunk == 1) {
    const int STR = 264;
    #pragma unroll
    for (int s = 0; s < 2; ++s) {
      #pragma unroll
      for (int mt2 = 0; mt2 < 2; ++mt2) {
        const int mt = s * 2 + mt2;
        float bz0 = 0.f, bz1 = 0.f;
        if (EPI == 1) {
          bz0 = bias1[bcol + wc * 64 + l31];
          bz1 = bias1[bcol + wc * 64 + 32 + l31];
        }
        #pragma unroll
        for (int r = 0; r < 16; ++r) {
          const int rloc = mt2 * 32 + (r & 3) + 8 * (r >> 2) + 4 * lhi;
          float rt = 1.f;
          if (EPI == 1) {
            const int rowg = brow + wr * 128 + s * 64 + rloc;
            rt = route[(size_t)rowg * E_ + (bcol >> 8)];
          }
          float v0 = acc[mt][0][r], v1 = acc[mt][1][r];
          if (EPI == 1) {
            v0 = fmaxf(v0 + bz0, 0.f) * rt;
            v1 = fmaxf(v1 + bz1, 0.f) * rt;
          }
          lds[(wr * 64 + rloc) * STR + wc * 64 + l31] = f2b(v0);
          lds[(wr * 64 + rloc) * STR + wc * 64 + 32 + l31] = f2b(v1);
        }
      }
      __syncthreads();
      #pragma unroll
      for (int i = 0; i < 8; ++i) {
        const int id = i * 512 + tid;           // 4096 x 16B chunks
        const int row = id >> 5, c16 = id & 31;
        const int g = row >> 6, rl = row & 63;
        *reinterpret_cast<short8*>(outB + (size_t)(brow + g * 128 + s * 64 + rl) * ldc +
                                   bcol + c16 * 8) =
            *reinterpret_cast<const short8*>(lds + row * STR + c16 * 8);
      }
      __syncthreads();
    }
  } else {
    const int STRF = 268;
    float* sF = reinterpret_cast<float*>(lds);
    #pragma unroll
    for (int s = 0; s < 4; ++s) {
      #pragma unroll
      for (int r = 0; r < 16; ++r) {
        const int rloc = (r & 3) + 8 * (r >> 2) + 4 * lhi;
        sF[(wr * 32 + rloc) * STRF + wc * 64 + l31] = acc[s][0][r];
        sF[(wr * 32 + rloc) * STRF + wc * 64 + 32 + l31] = acc[s][1][r];
      }
      __syncthreads();
      #pragma unroll
      for (int i = 0; i < 8; ++i) {
        const int id = i * 512 + tid;           // 4096 x 16B chunks
        const int row = id >> 6, c4 = id & 63;
        const int g = row >> 5, rl = row & 31;
        *reinterpret_cast<float4*>(outF + (size_t)(brow + g * 128 + s * 32 + rl) * ldc +
                                   bcol + c4 * 4) =
            *reinterpret_cast<const float4*>(sF + row * STRF + c4 * 4);
      }
      __syncthreads();
    }
  }
}

// ---------------- reduce: out += P1 + route @ b2 ----------------
__global__ __launch_bounds__(256)
void k_reduce(float* __restrict__ out, const bfu* __restrict__ P1,
              const float* __restrict__ route, const float* __restrict__ b2) {
  __shared__ float sb2[E_ * D_];   // 64 KiB
  for (int i = threadIdx.x; i < E_ * D_; i += 256) sb2[i] = b2[i];
  __syncthreads();
  const int total = (B_ * D_) / 4;
  for (int idx = blockIdx.x * 256 + threadIdx.x; idx < total; idx += gridDim.x * 256) {
    const int b = idx >> 8;
    const int d4 = (idx & 255) * 4;
    float4 o = reinterpret_cast<float4*>(out)[idx];
    ushort4 p = reinterpret_cast<const ushort4*>(P1)[idx];
    o.x += b2f(p.x); o.y += b2f(p.y); o.z += b2f(p.z); o.w += b2f(p.w);
    const float* rr = route + (size_t)b * E_;
    #pragma unroll
    for (int e = 0; e < E_; ++e) {
      const float r = rr[e];
      const float* bb = sb2 + e * D_ + d4;
      o.x = fmaf(r, bb[0], o.x);
      o.y = fmaf(r, bb[1], o.y);
      o.z = fmaf(r, bb[2], o.z);
      o.w = fmaf(r, bb[3], o.w);
    }
    reinterpret_cast<float4*>(out)[idx] = o;
  }
}

// ---------------- launch ----------------
extern "C" void kernel_launch(void* const* d_in, const int* in_sizes, int n_in,
                              void* d_out, int out_size, void* d_ws, size_t ws_size,
                              hipStream_t stream) {
  const float* x    = (const float*)d_in[0];
  const float* cond = (const float*)d_in[1];
  const float* W1   = (const float*)d_in[2];
  const float* b1   = (const float*)d_in[3];
  const float* W2   = (const float*)d_in[4];
  const float* b2   = (const float*)d_in[5];
  const float* Wr1  = (const float*)d_in[6];
  const float* br1  = (const float*)d_in[7];
  const float* Wr2  = (const float*)d_in[8];
  const float* br2  = (const float*)d_in[9];
  float* out = (float*)d_out;

  // ws layout (96.5 MB):
  // [Hp 64MB][W2t 8MB][route 0.5MB][W1b 8MB][xb 16MB (= P1 after GEMM1)]
  char* p = (char*)d_ws;
  bfu*   Hp    = (bfu*)p;                 p += (size_t)B_ * EH_ * 2;
  bfu*   W2t   = (bfu*)p;                 p += (size_t)D_ * EH_ * 2;
  float* route = (float*)p;               p += (size_t)B_ * E_ * 4;
  bfu*   W1b   = (bfu*)p;                 p += (size_t)EH_ * D_ * 2;
  bfu*   xb    = (bfu*)p;                 /* B_*D_*2 = 16MB */
  bfu*   P1b   = xb;                      // alias: xb dead after GEMM1

  k_prep<<<2048, 256, 0, stream>>>(x, xb, W1, W1b, W2, W2t);
  k_router<<<B_ / 16, 256, 0, stream>>>(cond, Wr1, br1, Wr2, br2, route);

  // GEMM1: Hp[8192,4096] = relu(xb @ W1b^T + b1) * route   (512 blocks)
  k_gemm8<1><<<dim3((B_ / 256) * (EH_ / 256)), 512, 0, stream>>>(
      xb, D_, W1b, D_, D_ / 64, nullptr, Hp, EH_, route, b1);

  // GEMM2: out/P1 = Hp @ W2t^T, split-K x2  (256 blocks)
  k_gemm8<2><<<dim3((B_ / 256) * (D_ / 256) * 2), 512, 0, stream>>>(
      Hp, EH_, W2t, EH_, (EH_ / 64) / 2, out, P1b, D_, nullptr, nullptr);

  // out += P1 + route @ b2
  k_reduce<<<2048, 256, 0, stream>>>(out, P1b, route, b2);
}